// Round 14
// baseline (27.319 us; speedup 1.0000x reference)
//
#include <hip/hip_runtime.h>

#define R 128
#define C 256
#define P 7
#define HW 64
#define SW 72             // slab row stride: phase-2 reads reach (6)*72+62+7 < 504
#define CHSLAB (P * SW)   // 504 floats per channel

__global__ __launch_bounds__(256) void
roi_pool_kernel(const float* __restrict__ x,
                const int* __restrict__ rois,
                float* __restrict__ out) {
    const int lane = threadIdx.x & 63;
    const int wid  = __builtin_amdgcn_readfirstlane(threadIdx.x >> 6);
    const int gw   = blockIdx.x * 4 + wid;    // wave id = r*128 + cpair
    const int cp = gw & 127;                  // channels 2cp, 2cp+1
    const int r  = gw >> 7;

    __shared__ float vmbuf[4][2 * CHSLAB];    // 16.1 KB/block -> 8 blocks/CU
    float* slab = vmbuf[wid];

    const int rx = rois[r * 4 + 0];           // r uniform -> s_loads
    const int ry = rois[r * 4 + 1];
    const int rw = rois[r * 4 + 2];
    const int rh = rois[r * 4 + 3];

    // Match JAX: f32 rn divide; floor(coord + i*rl) with separate rn mul+add.
    const float rlx = (float)rw / 7.0f;
    const float rly = (float)rh / 7.0f;
    const int kw = __builtin_amdgcn_readfirstlane((int)rlx);  // floor(rl), 1..8
    const int kh = __builtin_amdgcn_readfirstlane((int)rly);

    // Band starts: lane plays py for lanes 0..6; readlanes hoisted (uniform).
    const int syv = (int)floorf(__fadd_rn((float)ry, __fmul_rn((float)lane, rly)));
    const int sy0 = __builtin_amdgcn_readlane(syv, 0);
    const int sy1 = __builtin_amdgcn_readlane(syv, 1);
    const int sy2 = __builtin_amdgcn_readlane(syv, 2);
    const int sy3 = __builtin_amdgcn_readlane(syv, 3);
    const int sy4 = __builtin_amdgcn_readlane(syv, 4);
    const int sy5 = __builtin_amdgcn_readlane(syv, 5);
    const int sy6 = __builtin_amdgcn_readlane(syv, 6);

    // Lane split: half = channel (0/1), g = column pair (cols 2g, 2g+1).
    const int half = lane >> 5;
    const int g    = lane & 31;
    const float* base = x + ((size_t)((cp << 1) + half) << 12) + (g << 1);

    const float NEG = -3.402823466e38f;
    const float2 NEG2 = make_float2(NEG, NEG);

#define MAX2(a, b) make_float2(fmaxf((a).x,(b).x), fmaxf((a).y,(b).y))

    // ---- Phase 1: vertical band maxes; one load = 2 channels x 64 cols. ----
    // Rows always in-bounds (sy(6)+7 <= 62); rows >= kh discarded branch-free.
#define BAND(PY, SY, KH)                                                      \
    {                                                                         \
        const float* p = base + (SY) * HW;                                    \
        float2 v[KH];                                                         \
        _Pragma("unroll")                                                     \
        for (int j = 0; j < KH; ++j) v[j] = *(const float2*)(p + j * HW);     \
        float2 m = v[0];                      /* kh >= 1 */                   \
        _Pragma("unroll")                                                     \
        for (int j = 1; j < KH; ++j) {                                        \
            float2 t = (j < kh) ? v[j] : NEG2;                                \
            m = MAX2(m, t);                                                   \
        }                                                                     \
        *(float2*)(&slab[half * CHSLAB + (PY) * SW + (g << 1)]) = m;          \
    }

    if (kh <= 4) {
        BAND(0,sy0,4) BAND(1,sy1,4) BAND(2,sy2,4) BAND(3,sy3,4)
        BAND(4,sy4,4) BAND(5,sy5,4) BAND(6,sy6,4)
    } else {
        BAND(0,sy0,8) BAND(1,sy1,8) BAND(2,sy2,8) BAND(3,sy3,8)
        BAND(4,sy4,8) BAND(5,sy5,8) BAND(6,sy6,8)
    }
#undef BAND

    // ---- Phase 2: 49 lanes, 2 channel iterations; same-wave DS (lgkmcnt). ----
    // All 8 reads land inside the written/padded slab; slots >= kw discarded.
    if (lane < P * P) {
        const int py = lane / 7;
        const int px = lane - py * 7;
        const int sx = (int)floorf(__fadd_rn((float)rx, __fmul_rn((float)px, rlx)));
        const size_t obase = ((size_t)(r << 8) + (cp << 1)) * (P * P) + lane;

        #pragma unroll
        for (int cc = 0; cc < 2; ++cc) {
            const float* w = slab + cc * CHSLAB + py * SW + sx;
            float m;
            if (kw <= 4) {
                float a0 = w[0], a1 = w[1], a2 = w[2], a3 = w[3];
                m = a0;
                m = fmaxf(m, (1 < kw) ? a1 : NEG);
                m = fmaxf(m, (2 < kw) ? a2 : NEG);
                m = fmaxf(m, (3 < kw) ? a3 : NEG);
            } else {
                float a0 = w[0], a1 = w[1], a2 = w[2], a3 = w[3];
                float a4 = w[4], a5 = w[5], a6 = w[6], a7 = w[7];
                m = fmaxf(fmaxf(fmaxf(a0, a1), fmaxf(a2, a3)), a4);  // kw >= 5
                m = fmaxf(m, (5 < kw) ? a5 : NEG);
                m = fmaxf(m, (6 < kw) ? a6 : NEG);
                m = fmaxf(m, (7 < kw) ? a7 : NEG);
            }
            out[obase + cc * (P * P)] = m;    // 196B contiguous per store
        }
    }
}

extern "C" void kernel_launch(void* const* d_in, const int* in_sizes, int n_in,
                              void* d_out, int out_size, void* d_ws, size_t ws_size,
                              hipStream_t stream) {
    const float* x = (const float*)d_in[0];
    const int* rois = (const int*)d_in[1];
    float* out = (float*)d_out;

    const int grid = (R * C / 2) / 4;  // 16384 waves (r x 128 ch-pairs), 4/block
    roi_pool_kernel<<<grid, 256, 0, stream>>>(x, rois, out);
}

// Round 15
// 17.397 us; speedup vs baseline: 1.5703x; 1.5703x over previous
//
#include <hip/hip_runtime.h>

#define R 128
#define C 256
#define P 7
#define HW 64
#define SW 72   // slab row stride; overshoot reads stay inside LDS and are discarded

__global__ __launch_bounds__(256) void
roi_pool_kernel(const float* __restrict__ x,
                const int* __restrict__ rois,
                float* __restrict__ out) {
    __shared__ float xch[HW * HW];             // 16 KB: one full channel
    __shared__ float slabs[4 * P * SW + 16];   // per-wave band slabs + tail pad

    const int lane = threadIdx.x & 63;
    const int wid  = __builtin_amdgcn_readfirstlane(threadIdx.x >> 6);
    const int c    = blockIdx.x >> 3;          // channel 0..255
    const int rg   = blockIdx.x & 7;           // roi group (16 rois each)
    float* slab = slabs + wid * (P * SW);

    // ---- Stage channel c into LDS: 16 float4 loads per block, coalesced ----
    {
        const float4* src = (const float4*)(x + ((size_t)c << 12));
        float4* dst = (float4*)xch;
        const int t = threadIdx.x;
        #pragma unroll
        for (int i = 0; i < 4; ++i) dst[t + i * 256] = src[t + i * 256];
    }
    __syncthreads();

    const float NEG = -3.402823466e38f;

    // ---- 4 ROIs per wave, fully from LDS ----
    #pragma unroll
    for (int k = 0; k < 4; ++k) {
        const int r = (rg << 4) + (wid << 2) + k;    // wave-uniform scalar
        const int rx = rois[r * 4 + 0];              // s_loads
        const int ry = rois[r * 4 + 1];
        const int rw = rois[r * 4 + 2];
        const int rh = rois[r * 4 + 3];

        // Match JAX: f32 rn divide; floor(coord + i*rl), separate rn mul+add.
        const float rlx = (float)rw / 7.0f;
        const float rly = (float)rh / 7.0f;
        const int kw = __builtin_amdgcn_readfirstlane((int)rlx);  // 1..8
        const int kh = __builtin_amdgcn_readfirstlane((int)rly);

        const int syv = (int)floorf(__fadd_rn((float)ry, __fmul_rn((float)lane, rly)));
        const int sy0 = __builtin_amdgcn_readlane(syv, 0);
        const int sy1 = __builtin_amdgcn_readlane(syv, 1);
        const int sy2 = __builtin_amdgcn_readlane(syv, 2);
        const int sy3 = __builtin_amdgcn_readlane(syv, 3);
        const int sy4 = __builtin_amdgcn_readlane(syv, 4);
        const int sy5 = __builtin_amdgcn_readlane(syv, 5);
        const int sy6 = __builtin_amdgcn_readlane(syv, 6);

        // Phase 1: vertical band maxes from LDS; lane = column, stride-1
        // (conflict-free). KH rows read unconditionally; rows >= kh and any
        // overshoot (index <= 65*64+63 = 4223 < LDS size) are discarded.
#define BAND(PY, SY, KH)                                                      \
        {                                                                     \
            const float* p = xch + (SY) * HW + lane;                          \
            float v[KH];                                                      \
            _Pragma("unroll")                                                 \
            for (int j = 0; j < KH; ++j) v[j] = p[j * HW];                    \
            float vm = v[0];                  /* kh >= 1 */                   \
            _Pragma("unroll")                                                 \
            for (int j = 1; j < KH; ++j) vm = fmaxf(vm, (j < kh) ? v[j] : NEG); \
            slab[(PY) * SW + lane] = vm;                                      \
        }

        if (kh <= 4) {
            BAND(0,sy0,4) BAND(1,sy1,4) BAND(2,sy2,4) BAND(3,sy3,4)
            BAND(4,sy4,4) BAND(5,sy5,4) BAND(6,sy6,4)
        } else {
            BAND(0,sy0,8) BAND(1,sy1,8) BAND(2,sy2,8) BAND(3,sy3,8)
            BAND(4,sy4,8) BAND(5,sy5,8) BAND(6,sy6,8)
        }
#undef BAND

        // Phase 2: one lane per bin; same-wave DS ordering via lgkmcnt.
        // All 8 reads stay inside the LDS allocation; slots >= kw discarded.
        if (lane < P * P) {
            const int py = lane / 7;
            const int px = lane - py * 7;
            const int sx = (int)floorf(__fadd_rn((float)rx, __fmul_rn((float)px, rlx)));
            const float* w = slab + py * SW + sx;
            float m;
            if (kw <= 4) {
                float a0 = w[0], a1 = w[1], a2 = w[2], a3 = w[3];
                m = a0;
                m = fmaxf(m, (1 < kw) ? a1 : NEG);
                m = fmaxf(m, (2 < kw) ? a2 : NEG);
                m = fmaxf(m, (3 < kw) ? a3 : NEG);
            } else {
                float a0 = w[0], a1 = w[1], a2 = w[2], a3 = w[3];
                float a4 = w[4], a5 = w[5], a6 = w[6], a7 = w[7];
                m = fmaxf(fmaxf(fmaxf(a0, a1), fmaxf(a2, a3)), a4);  // kw >= 5
                m = fmaxf(m, (5 < kw) ? a5 : NEG);
                m = fmaxf(m, (6 < kw) ? a6 : NEG);
                m = fmaxf(m, (7 < kw) ? a7 : NEG);
            }
            out[((size_t)((r << 8) + c)) * (P * P) + lane] = m;  // 196B contig
        }
    }
}

extern "C" void kernel_launch(void* const* d_in, const int* in_sizes, int n_in,
                              void* d_out, int out_size, void* d_ws, size_t ws_size,
                              hipStream_t stream) {
    const float* x = (const float*)d_in[0];
    const int* rois = (const int*)d_in[1];
    float* out = (float*)d_out;

    const int grid = C * 8;   // 2048 blocks: (channel) x (8 groups of 16 rois)
    roi_pool_kernel<<<grid, 256, 0, stream>>>(x, rois, out);
}